// Round 7
// baseline (509.782 us; speedup 1.0000x reference)
//
#include <hip/hip_runtime.h>

typedef unsigned short u16;
typedef __bf16 bf16x8 __attribute__((ext_vector_type(8)));
typedef unsigned short us8 __attribute__((ext_vector_type(8)));
typedef float f32x4 __attribute__((ext_vector_type(4)));

#define GLD16(gptr, lptr)                                                              \
  __builtin_amdgcn_global_load_lds((const __attribute__((address_space(1))) void*)(gptr), \
                                   (__attribute__((address_space(3))) void*)(lptr), 16, 0, 0)

#define MFMA_BF16(a, b, c) __builtin_amdgcn_mfma_f32_16x16x32_bf16((a), (b), (c), 0, 0, 0)

static __device__ __forceinline__ u16 f2bf(float f) {  // f32 -> bf16 RNE
  unsigned int u = __float_as_uint(f);
  u += 0x7fffu + ((u >> 16) & 1u);
  return (u16)(u >> 16);
}
static __device__ __forceinline__ float bf2f(u16 h) {
  return __uint_as_float(((unsigned int)h) << 16);
}

// ---------------- prep: split x into bf16 hi/lo, granule-swizzled for conflict-free LDS reads ----
// within each 32-elem K-block, 8-elem granule q is stored at q' = q ^ ((row>>1)&3)
__global__ __launch_bounds__(256) void k_split_x(const float* __restrict__ x,
                                                 u16* __restrict__ xh, u16* __restrict__ xl) {
  size_t i = (size_t)blockIdx.x * 256 + threadIdx.x;  // granule of 8 floats; 128 granules/row
  const float4* xf = (const float4*)x;
  float4 a = xf[2 * i], b = xf[2 * i + 1];
  float vv[8] = {a.x, a.y, a.z, a.w, b.x, b.y, b.z, b.w};
  us8 H, L;
#pragma unroll
  for (int j = 0; j < 8; ++j) {
    u16 hi = f2bf(vv[j]);
    H[j] = hi;
    L[j] = f2bf(vv[j] - bf2f(hi));
  }
  const int row = (int)(i >> 7);
  const int qp = ((int)i & 3) ^ ((row >> 1) & 3);
  const size_t dst = (i & ~(size_t)3) | (size_t)qp;
  *(us8*)(xh + dst * 8) = H;
  *(us8*)(xl + dst * 8) = L;
}

// ---------------- prep: transpose W1 [1024][2048] -> W1T [2048][1024], split hi/lo, swizzled ----
__global__ __launch_bounds__(256) void k_split_w1t(const float* __restrict__ w1,
                                                   u16* __restrict__ wh, u16* __restrict__ wl) {
  __shared__ float tile[32][33];
  int bn = blockIdx.x & 63;   // n tile (2048/32)
  int bk = blockIdx.x >> 6;   // k tile (1024/32)
  int tn = threadIdx.x & 31, tq = threadIdx.x >> 5;  // tq 0..7
#pragma unroll
  for (int r = 0; r < 4; ++r) {
    int k = bk * 32 + tq + r * 8;
    tile[tq + r * 8][tn] = w1[(size_t)k * 2048 + bn * 32 + tn];
  }
  __syncthreads();
#pragma unroll
  for (int r = 0; r < 4; ++r) {
    int n = bn * 32 + tq + r * 8;
    float v = tile[tn][tq + r * 8];
    u16 hi = f2bf(v);
    int qp = (tn >> 3) ^ ((n >> 1) & 3);
    int kp = bk * 32 + qp * 8 + (tn & 7);
    wh[(size_t)n * 1024 + kp] = hi;
    wl[(size_t)n * 1024 + kp] = f2bf(v - bf2f(hi));
  }
}

// ---------------- prep: W2g = g1*W2 in MFMA B-fragment order (16x16x32), split hi/lo ----------------
// frag[(c*64 + lane)*8 + j] = B[k = c*32 + 8*(lane>>4) + j][col = lane&15], cols 9..15 zero
__global__ __launch_bounds__(256) void k_w2frag(const float* __restrict__ w2, const float* __restrict__ g1,
                                                u16* __restrict__ fh, u16* __restrict__ fl) {
  int t = blockIdx.x * 256 + threadIdx.x;  // 0..4095
  int c = t >> 6, l = t & 63;
  int col = l & 15, lg = l >> 4;
  us8 H, L;
#pragma unroll
  for (int j = 0; j < 8; ++j) {
    int k = c * 32 + lg * 8 + j;
    float v = (col < 9) ? g1[k] * w2[k * 9 + col] : 0.f;
    u16 hi = f2bf(v);
    H[j] = hi;
    L[j] = f2bf(v - bf2f(hi));
  }
  *(us8*)(fh + (size_t)t * 8) = H;
  *(us8*)(fl + (size_t)t * 8) = L;
}

// ---------------- prep: cg[j] = sum_k g1[k]*W2[k][j], cb[j] = sum_k be1[k]*W2[k][j]  (f64) ----------------
__global__ void k_cgcb(const float* __restrict__ w2, const float* __restrict__ g1,
                       const float* __restrict__ be1, double* __restrict__ cgcb) {
  int l = threadIdx.x;  // 64 threads, 1 block
  double cg[9], cb[9];
#pragma unroll
  for (int j = 0; j < 9; ++j) { cg[j] = 0.0; cb[j] = 0.0; }
  for (int i = 0; i < 32; ++i) {
    int k = i * 64 + l;
    double g = (double)g1[k], b = (double)be1[k];
#pragma unroll
    for (int j = 0; j < 9; ++j) {
      double w = (double)w2[k * 9 + j];
      cg[j] += g * w;
      cb[j] += b * w;
    }
  }
  for (int off = 32; off; off >>= 1) {
#pragma unroll
    for (int j = 0; j < 9; ++j) {
      cg[j] += __shfl_xor(cg[j], off, 64);
      cb[j] += __shfl_xor(cb[j], off, 64);
    }
  }
  if (l == 0) {
    for (int j = 0; j < 16; ++j) {
      cgcb[j] = (j < 9) ? cg[j] : 0.0;
      cgcb[16 + j] = (j < 9) ? cb[j] : 0.0;
    }
  }
}

// ---------------- GEMM1 + fused GEMM2-partial: 4-term split-bf16, 16x16x32 MFMA ----------------
// 128x128 tile, BK=32, 4 waves (2x2 of 64x64), 64 KiB LDS -> 2 blocks/CU (two independent
// barrier domains per CU). Round-5 K-loop shape: counted vmcnt(2), dbuf, raw barriers,
// STAGE interleaved with MFMA clusters, granule swizzle (proven 0-conflict).
// Epilogue: relu -> LDS f32 tile [128][128] -> GEMM2 partial dots + stats.
__global__ __launch_bounds__(256, 2) void k_gemm1(const u16* __restrict__ xh, const u16* __restrict__ xl,
                                                  const u16* __restrict__ wh, const u16* __restrict__ wl,
                                                  const float* __restrict__ b1,
                                                  const u16* __restrict__ fh, const u16* __restrict__ fl,
                                                  float* __restrict__ pdot, float* __restrict__ pstat) {
  __shared__ __align__(16) u16 lds[2][4][4096];  // [buf][Ah,Al,Bh,Bl][128 rows * 32 k] = 64 KiB
  const int tid = threadIdx.x;
  // XCD swizzle (bijective, nwg=4096): per-XCD chunk = 512 blocks, n-tile fastest (A L2 reuse)
  const int swz = ((blockIdx.x & 7) << 9) | (blockIdx.x >> 3);
  const int m0 = (swz >> 4) << 7;   // 256 m-tiles
  const int n0 = (swz & 15) << 7;   // 16 n-tiles
  const int lane = tid & 63, w = tid >> 6;
  const int wr = (w >> 1) << 6;  // 0 or 64
  const int wc = (w & 1) << 6;   // 0 or 64
  const int lr = lane & 15, lg = lane >> 4;

  // tile-invariant LDS read offsets (u16 units), with conflict swizzle
  int a_off[4], b_off[4];
#pragma unroll
  for (int i = 0; i < 4; ++i) {
    int row = wr + i * 16 + lr;
    a_off[i] = row * 32 + ((lg ^ ((row >> 1) & 3)) << 3);
  }
#pragma unroll
  for (int j = 0; j < 4; ++j) {
    int row = wc + j * 16 + lr;
    b_off[j] = row * 32 + ((lg ^ ((row >> 1) & 3)) << 3);
  }

  // staging: 2 granules (16B) per thread per matrix; rows tid>>2 and tid>>2+64
  const size_t aoff = (size_t)(m0 + (tid >> 2)) * 1024 + ((tid & 3) << 3);
  const size_t boff = (size_t)(n0 + (tid >> 2)) * 1024 + ((tid & 3) << 3);

#define STAGE1(bf, mt, src, off, kk)                          \
  do {                                                        \
    GLD16((src) + (off) + (kk), &lds[bf][mt][tid * 8]);       \
    GLD16((src) + (off) + 65536 + (kk), &lds[bf][mt][2048 + tid * 8]); \
  } while (0)

  // prologue: stage K-tile 0 into buf 0 (8 loads/thread, oldest in vmcnt order)
  STAGE1(0, 0, xh, aoff, 0);
  STAGE1(0, 1, xl, aoff, 0);
  STAGE1(0, 2, wh, boff, 0);
  STAGE1(0, 3, wl, boff, 0);

  f32x4 acc[4][4] = {};
#pragma unroll 2
  for (int kt = 0; kt < 32; ++kt) {
    const int cur = kt & 1, nxt = cur ^ 1;
    const int nk = (kt < 31 ? kt + 1 : 31) * 32;  // last iter: benign re-stage of tile 31
    // prefetch next tile Ah BEFORE the wait -> these stay in flight across the barrier
    STAGE1(nxt, 0, xh, aoff, nk);
    asm volatile("s_waitcnt vmcnt(2)" ::: "memory");  // retire current tile's 8 loads only
    __builtin_amdgcn_s_barrier();                     // raw: no vmcnt(0) drain
    asm volatile("" ::: "memory");
    const u16* Ah = &lds[cur][0][0];
    const u16* Al = &lds[cur][1][0];
    const u16* Bh = &lds[cur][2][0];
    const u16* Bl = &lds[cur][3][0];
    bf16x8 ahf[4], alf[4], bhf[4], blf[4];
#pragma unroll
    for (int j = 0; j < 4; ++j) {
      bhf[j] = *(const bf16x8*)(Bh + b_off[j]);
      blf[j] = *(const bf16x8*)(Bl + b_off[j]);
    }
#pragma unroll
    for (int i = 0; i < 4; ++i) {
      ahf[i] = *(const bf16x8*)(Ah + a_off[i]);
      alf[i] = *(const bf16x8*)(Al + a_off[i]);
    }
    // P0: prefetch Al; MFMA i0-1 x all j
    STAGE1(nxt, 1, xl, aoff, nk);
    __builtin_amdgcn_s_setprio(1);
#pragma unroll
    for (int i = 0; i < 2; ++i)
#pragma unroll
      for (int j = 0; j < 4; ++j) {
        acc[i][j] = MFMA_BF16(ahf[i], bhf[j], acc[i][j]);
        acc[i][j] = MFMA_BF16(ahf[i], blf[j], acc[i][j]);
        acc[i][j] = MFMA_BF16(alf[i], bhf[j], acc[i][j]);
        acc[i][j] = MFMA_BF16(alf[i], blf[j], acc[i][j]);
      }
    __builtin_amdgcn_s_setprio(0);
    // P1: prefetch Bh; MFMA i=2
    STAGE1(nxt, 2, wh, boff, nk);
    __builtin_amdgcn_s_setprio(1);
#pragma unroll
    for (int j = 0; j < 4; ++j) {
      acc[2][j] = MFMA_BF16(ahf[2], bhf[j], acc[2][j]);
      acc[2][j] = MFMA_BF16(ahf[2], blf[j], acc[2][j]);
      acc[2][j] = MFMA_BF16(alf[2], bhf[j], acc[2][j]);
      acc[2][j] = MFMA_BF16(alf[2], blf[j], acc[2][j]);
    }
    __builtin_amdgcn_s_setprio(0);
    // P2: prefetch Bl; MFMA i=3
    STAGE1(nxt, 3, wl, boff, nk);
    __builtin_amdgcn_s_setprio(1);
#pragma unroll
    for (int j = 0; j < 4; ++j) {
      acc[3][j] = MFMA_BF16(ahf[3], bhf[j], acc[3][j]);
      acc[3][j] = MFMA_BF16(ahf[3], blf[j], acc[3][j]);
      acc[3][j] = MFMA_BF16(alf[3], bhf[j], acc[3][j]);
      acc[3][j] = MFMA_BF16(alf[3], blf[j], acc[3][j]);
    }
    __builtin_amdgcn_s_setprio(0);
    asm volatile("" ::: "memory");
    __builtin_amdgcn_s_barrier();  // all waves done reading buf[cur] -> next tile may overwrite
  }
#undef STAGE1

  // ======== fused epilogue: relu + GEMM2-partial + stats (no hbuf) ========
  asm volatile("s_waitcnt vmcnt(0)" ::: "memory");  // drain in-flight global_load_lds
  __syncthreads();                                  // LDS now free for reuse
  float* vt = (float*)&lds[0][0][0];                // [128 rows][128 cols f32], granule-swizzled

  // E0: bias + relu in place
#pragma unroll
  for (int j = 0; j < 4; ++j) {
    const float bias = b1[n0 + wc + j * 16 + lr];
#pragma unroll
    for (int i = 0; i < 4; ++i)
#pragma unroll
      for (int r = 0; r < 4; ++r) acc[i][j][r] = fmaxf(acc[i][j][r] + bias, 0.f);
  }

  // write phase: each wave writes its 64x64 quadrant (swizzled granules)
#pragma unroll
  for (int j = 0; j < 4; ++j) {
    const int lcol = wc + j * 16 + lr;
    const int g = lcol >> 2, wsel = lcol & 3;
#pragma unroll
    for (int i = 0; i < 4; ++i)
#pragma unroll
      for (int r = 0; r < 4; ++r) {
        const int row = wr + i * 16 + lg * 4 + r;
        vt[row * 128 + ((g ^ (row & 7)) << 2) + wsel] = acc[i][j][r];
      }
  }
  __syncthreads();

  // read phase: each wave owns rows [w*32, w*32+32); 4 k-blocks of 32 cols
  f32x4 acc2[2] = {};
  float sstat[2] = {0.f, 0.f}, qstat[2] = {0.f, 0.f};
  const int myrow0 = w * 32;
#pragma unroll
  for (int cl = 0; cl < 4; ++cl) {
    const int cglob = (n0 >> 5) + cl;
    const bf16x8 bh = *(const bf16x8*)(fh + (size_t)(cglob * 64 + lane) * 8);
    const bf16x8 bl = *(const bf16x8*)(fl + (size_t)(cglob * 64 + lane) * 8);
#pragma unroll
    for (int g2 = 0; g2 < 2; ++g2) {
      const int row = myrow0 + g2 * 16 + lr;
      const int g0 = cl * 8 + lg * 2;
      const float4 f0 = *(const float4*)&vt[row * 128 + ((g0 ^ (row & 7)) << 2)];
      const float4 f1 = *(const float4*)&vt[row * 128 + (((g0 + 1) ^ (row & 7)) << 2)];
      float f[8] = {f0.x, f0.y, f0.z, f0.w, f1.x, f1.y, f1.z, f1.w};
      us8 HH, LL;
#pragma unroll
      for (int e = 0; e < 8; ++e) {
        sstat[g2] += f[e];
        qstat[g2] = fmaf(f[e], f[e], qstat[g2]);
        u16 hi = f2bf(f[e]);
        HH[e] = hi;
        LL[e] = f2bf(f[e] - bf2f(hi));
      }
      bf16x8 ah = __builtin_bit_cast(bf16x8, HH);
      bf16x8 al = __builtin_bit_cast(bf16x8, LL);
      acc2[g2] = MFMA_BF16(ah, bh, acc2[g2]);
      acc2[g2] = MFMA_BF16(ah, bl, acc2[g2]);
      acc2[g2] = MFMA_BF16(al, bh, acc2[g2]);
      acc2[g2] = MFMA_BF16(al, bl, acc2[g2]);
    }
  }

  // stats reduce over the 4 lg-lanes (same lr = same row)
#pragma unroll
  for (int g2 = 0; g2 < 2; ++g2) {
    sstat[g2] += __shfl_xor(sstat[g2], 16, 64);
    sstat[g2] += __shfl_xor(sstat[g2], 32, 64);
    qstat[g2] += __shfl_xor(qstat[g2], 16, 64);
    qstat[g2] += __shfl_xor(qstat[g2], 32, 64);
  }
  const int ntile = n0 >> 7;  // 16 n-tiles
#pragma unroll
  for (int g2 = 0; g2 < 2; ++g2) {
    if (lg == 0) {
      const int row = m0 + myrow0 + g2 * 16 + lr;
      *(float2*)&pstat[((size_t)row * 16 + ntile) * 2] = make_float2(sstat[g2], qstat[g2]);
    }
    if (lr < 9) {
#pragma unroll
      for (int r = 0; r < 4; ++r) {
        const int row = m0 + myrow0 + g2 * 16 + lg * 4 + r;
        pdot[((size_t)row * 16 + ntile) * 12 + lr] = acc2[g2][r];
      }
    }
  }
}

// ---------------- f64 3x3 SVD -> nearest SO(3) rotation ----------------
static __device__ __forceinline__ void jrot(double S[3][3], double V[3][3], int p, int q, int r) {
  double apq = S[p][q];
  if (apq == 0.0) return;
  double tau = (S[q][q] - S[p][p]) / (2.0 * apq);
  double t = (tau >= 0.0 ? 1.0 : -1.0) / (fabs(tau) + sqrt(1.0 + tau * tau));
  double c = 1.0 / sqrt(1.0 + t * t);
  double s = t * c;
  double spp = S[p][p], sqq = S[q][q];
  double srp = S[r][p], srq = S[r][q];
  S[p][p] = spp - t * apq;
  S[q][q] = sqq + t * apq;
  S[p][q] = 0.0; S[q][p] = 0.0;
  S[r][p] = c * srp - s * srq; S[p][r] = S[r][p];
  S[r][q] = s * srp + c * srq; S[q][r] = S[r][q];
#pragma unroll
  for (int i = 0; i < 3; ++i) {
    double vip = V[i][p], viq = V[i][q];
    V[i][p] = c * vip - s * viq;
    V[i][q] = s * vip + c * viq;
  }
}

static __device__ void svd_so3(const double* Rf, float* Of) {
  double A[3][3], S[3][3];
  double V[3][3] = {{1, 0, 0}, {0, 1, 0}, {0, 0, 1}};
#pragma unroll
  for (int i = 0; i < 3; ++i)
#pragma unroll
    for (int j = 0; j < 3; ++j) A[i][j] = Rf[i * 3 + j];
#pragma unroll
  for (int p = 0; p < 3; ++p)
#pragma unroll
    for (int q = 0; q < 3; ++q) {
      double sa = 0.0;
#pragma unroll
      for (int i = 0; i < 3; ++i) sa += A[i][p] * A[i][q];
      S[p][q] = sa;
    }
  for (int it = 0; it < 6; ++it) {
    jrot(S, V, 0, 1, 2);
    jrot(S, V, 0, 2, 1);
    jrot(S, V, 1, 2, 0);
  }
  double l0 = S[0][0], l1 = S[1][1], l2 = S[2][2];
  double c0[3] = {V[0][0], V[1][0], V[2][0]};
  double c1[3] = {V[0][1], V[1][1], V[2][1]};
  double c2[3] = {V[0][2], V[1][2], V[2][2]};
  double tl, tv;
#define SWP(la, lb, ca, cb)                                         \
  if (la < lb) {                                                    \
    tl = la; la = lb; lb = tl;                                      \
    tv = ca[0]; ca[0] = cb[0]; cb[0] = tv;                          \
    tv = ca[1]; ca[1] = cb[1]; cb[1] = tv;                          \
    tv = ca[2]; ca[2] = cb[2]; cb[2] = tv;                          \
  }
  SWP(l0, l1, c0, c1)
  SWP(l0, l2, c0, c2)
  SWP(l1, l2, c1, c2)
#undef SWP
  double v3[3];
  v3[0] = c0[1] * c1[2] - c0[2] * c1[1];
  v3[1] = c0[2] * c1[0] - c0[0] * c1[2];
  v3[2] = c0[0] * c1[1] - c0[1] * c1[0];
  double t1[3], t2[3];
#pragma unroll
  for (int i = 0; i < 3; ++i) {
    t1[i] = A[i][0] * c0[0] + A[i][1] * c0[1] + A[i][2] * c0[2];
    t2[i] = A[i][0] * c1[0] + A[i][1] * c1[1] + A[i][2] * c1[2];
  }
  double n1 = sqrt(t1[0] * t1[0] + t1[1] * t1[1] + t1[2] * t1[2]);
  if (n1 < 1e-20) {
#pragma unroll
    for (int t = 0; t < 9; ++t) Of[t] = (t == 0 || t == 4 || t == 8) ? 1.f : 0.f;
    return;
  }
  double u1[3], u2[3], u3[3];
  double r1 = 1.0 / n1;
#pragma unroll
  for (int i = 0; i < 3; ++i) u1[i] = t1[i] * r1;
  double d12 = u1[0] * t2[0] + u1[1] * t2[1] + u1[2] * t2[2];
#pragma unroll
  for (int i = 0; i < 3; ++i) t2[i] -= d12 * u1[i];
  double n2 = sqrt(t2[0] * t2[0] + t2[1] * t2[1] + t2[2] * t2[2]);
  if (n2 > 1e-14 * n1) {
    double r2 = 1.0 / n2;
#pragma unroll
    for (int i = 0; i < 3; ++i) u2[i] = t2[i] * r2;
  } else {
    double ax = fabs(u1[0]), ay = fabs(u1[1]), az = fabs(u1[2]);
    double e[3] = {0.0, 0.0, 0.0};
    if (ax <= ay && ax <= az) e[0] = 1.0;
    else if (ay <= az) e[1] = 1.0;
    else e[2] = 1.0;
    double d = e[0] * u1[0] + e[1] * u1[1] + e[2] * u1[2];
#pragma unroll
    for (int i = 0; i < 3; ++i) e[i] -= d * u1[i];
    double nn = 1.0 / sqrt(e[0] * e[0] + e[1] * e[1] + e[2] * e[2]);
#pragma unroll
    for (int i = 0; i < 3; ++i) u2[i] = e[i] * nn;
  }
  u3[0] = u1[1] * u2[2] - u1[2] * u2[1];
  u3[1] = u1[2] * u2[0] - u1[0] * u2[2];
  u3[2] = u1[0] * u2[1] - u1[1] * u2[0];
#pragma unroll
  for (int i = 0; i < 3; ++i)
#pragma unroll
    for (int j = 0; j < 3; ++j)
      Of[i * 3 + j] = (float)(u1[i] * c0[j] + u2[i] * c1[j] + u3[i] * v3[j]);
}

// ---------------- combine: f64 sum of partials + LN1-fold + LN2 + SVD, 1 thread/row ----------------
__global__ __launch_bounds__(256) void k_comb(const float* __restrict__ pdot,
                                              const float* __restrict__ pstat,
                                              const double* __restrict__ cgcb,
                                              const float* __restrict__ b2,
                                              const float* __restrict__ g2v,
                                              const float* __restrict__ be2,
                                              float* __restrict__ out) {
  const int row = blockIdx.x * 256 + threadIdx.x;
  double dj[9];
#pragma unroll
  for (int j = 0; j < 9; ++j) dj[j] = 0.0;
  double s = 0.0, q = 0.0;
#pragma unroll
  for (int nt = 0; nt < 16; ++nt) {
    const float* p = pdot + ((size_t)row * 16 + nt) * 12;
#pragma unroll
    for (int j = 0; j < 9; ++j) dj[j] += (double)p[j];
    const float* ps = pstat + ((size_t)row * 16 + nt) * 2;
    s += (double)ps[0];
    q += (double)ps[1];
  }
  const double mean = s * (1.0 / 2048.0);
  const double varr = fmax(q * (1.0 / 2048.0) - mean * mean, 0.0);
  const double inv = 1.0 / sqrt(varr + 1e-5);
  double a2[9];
  double s9 = 0.0, q9 = 0.0;
#pragma unroll
  for (int j = 0; j < 9; ++j) {
    double v = inv * (dj[j] - mean * cgcb[j]) + cgcb[16 + j] + (double)b2[j];
    v = fmax(v, 0.0);
    a2[j] = v;
    s9 += v;
    q9 += v * v;
  }
  const double m2 = s9 * (1.0 / 9.0);
  const double v2c = fmax(q9 * (1.0 / 9.0) - m2 * m2, 0.0);
  const double i2 = 1.0 / sqrt(v2c + 1e-5);
  double rn[9];
#pragma unroll
  for (int j = 0; j < 9; ++j) rn[j] = (a2[j] - m2) * i2 * (double)g2v[j] + (double)be2[j];
  float O[9];
  svd_so3(rn, O);
  float* op = out + (size_t)row * 9;
#pragma unroll
  for (int t = 0; t < 9; ++t) op[t] = O[t];
}

// ---------------- host ----------------
extern "C" void kernel_launch(void* const* d_in, const int* in_sizes, int n_in,
                              void* d_out, int out_size, void* d_ws, size_t ws_size,
                              hipStream_t stream) {
  const float* x   = (const float*)d_in[0];
  const float* W1  = (const float*)d_in[1];
  const float* b1  = (const float*)d_in[2];
  const float* g1  = (const float*)d_in[3];
  const float* be1 = (const float*)d_in[4];
  const float* W2  = (const float*)d_in[5];
  const float* b2  = (const float*)d_in[6];
  const float* g2  = (const float*)d_in[7];
  const float* be2 = (const float*)d_in[8];
  float* out = (float*)d_out;
  char* ws = (char*)d_ws;
  u16*    xh   = (u16*)(ws + 0);             // 67108864 B
  u16*    xl   = (u16*)(ws + 67108864);      // 67108864
  u16*    wh   = (u16*)(ws + 134217728);     // 4194304
  u16*    wl   = (u16*)(ws + 138412032);     // 4194304
  u16*    fh   = (u16*)(ws + 142606336);     // 65536
  u16*    fl   = (u16*)(ws + 142671872);     // 65536
  double* cgcb = (double*)(ws + 142737408);  // 256 B
  float*  pdot = (float*)(ws + 142737664);   // 32768*16*12*4 = 25165824
  float*  pstat= (float*)(ws + 167903488);   // 32768*16*2*4  = 4194304

  k_split_x<<<dim3(16384), dim3(256), 0, stream>>>(x, xh, xl);
  k_split_w1t<<<dim3(2048), dim3(256), 0, stream>>>(W1, wh, wl);
  k_w2frag<<<dim3(16), dim3(256), 0, stream>>>(W2, g1, fh, fl);
  k_cgcb<<<dim3(1), dim3(64), 0, stream>>>(W2, g1, be1, cgcb);
  k_gemm1<<<dim3(4096), dim3(256), 0, stream>>>(xh, xl, wh, wl, b1, fh, fl, pdot, pstat);
  k_comb<<<dim3(128), dim3(256), 0, stream>>>(pdot, pstat, cgcb, b2, g2, be2, out);
}

// Round 8
// 396.241 us; speedup vs baseline: 1.2865x; 1.2865x over previous
//
#include <hip/hip_runtime.h>

typedef unsigned short u16;
typedef _Float16 f16x8 __attribute__((ext_vector_type(8)));
typedef unsigned short us8 __attribute__((ext_vector_type(8)));
typedef float f32x4 __attribute__((ext_vector_type(4)));

#define GLD16(gptr, lptr)                                                              \
  __builtin_amdgcn_global_load_lds((const __attribute__((address_space(1))) void*)(gptr), \
                                   (__attribute__((address_space(3))) void*)(lptr), 16, 0, 0)

#define MFMA_F16(a, b, c) __builtin_amdgcn_mfma_f32_16x16x32_f16((a), (b), (c), 0, 0, 0)

// ---------------- prep: split x into fp16 hi/lo, granule-swizzled for conflict-free LDS reads ----
// within each 32-elem K-block, 8-elem granule q is stored at q' = q ^ ((row>>1)&3)
__global__ __launch_bounds__(256) void k_split_x(const float* __restrict__ x,
                                                 u16* __restrict__ xh, u16* __restrict__ xl) {
  size_t i = (size_t)blockIdx.x * 256 + threadIdx.x;  // granule of 8 floats; 128 granules/row
  const float4* xf = (const float4*)x;
  float4 a = xf[2 * i], b = xf[2 * i + 1];
  float vv[8] = {a.x, a.y, a.z, a.w, b.x, b.y, b.z, b.w};
  f16x8 H, L;
#pragma unroll
  for (int j = 0; j < 8; ++j) {
    _Float16 hi = (_Float16)vv[j];
    H[j] = hi;
    L[j] = (_Float16)(vv[j] - (float)hi);
  }
  const int row = (int)(i >> 7);
  const int qp = ((int)i & 3) ^ ((row >> 1) & 3);
  const size_t dst = (i & ~(size_t)3) | (size_t)qp;
  *(f16x8*)(xh + dst * 8) = H;
  *(f16x8*)(xl + dst * 8) = L;
}

// ---------------- prep: transpose W1 [1024][2048] -> W1T [2048][1024], split fp16 hi/lo, swizzled ----
__global__ __launch_bounds__(256) void k_split_w1t(const float* __restrict__ w1,
                                                   u16* __restrict__ wh, u16* __restrict__ wl) {
  __shared__ float tile[32][33];
  int bn = blockIdx.x & 63;   // n tile (2048/32)
  int bk = blockIdx.x >> 6;   // k tile (1024/32)
  int tn = threadIdx.x & 31, tq = threadIdx.x >> 5;  // tq 0..7
#pragma unroll
  for (int r = 0; r < 4; ++r) {
    int k = bk * 32 + tq + r * 8;
    tile[tq + r * 8][tn] = w1[(size_t)k * 2048 + bn * 32 + tn];
  }
  __syncthreads();
#pragma unroll
  for (int r = 0; r < 4; ++r) {
    int n = bn * 32 + tq + r * 8;
    float v = tile[tn][tq + r * 8];
    _Float16 hi = (_Float16)v;
    _Float16 lo = (_Float16)(v - (float)hi);
    int qp = (tn >> 3) ^ ((n >> 1) & 3);
    int kp = bk * 32 + qp * 8 + (tn & 7);
    wh[(size_t)n * 1024 + kp] = __builtin_bit_cast(u16, hi);
    wl[(size_t)n * 1024 + kp] = __builtin_bit_cast(u16, lo);
  }
}

// ---------------- prep: W2g = g1*W2 in MFMA B-fragment order (16x16x32), split fp16 hi/lo ----------------
// frag[(c*64 + lane)*8 + j] = B[k = c*32 + 8*(lane>>4) + j][col = lane&15], cols 9..15 zero
__global__ __launch_bounds__(256) void k_w2frag(const float* __restrict__ w2, const float* __restrict__ g1,
                                                u16* __restrict__ fh, u16* __restrict__ fl) {
  int t = blockIdx.x * 256 + threadIdx.x;  // 0..4095
  int c = t >> 6, l = t & 63;
  int col = l & 15, lg = l >> 4;
  f16x8 H, L;
#pragma unroll
  for (int j = 0; j < 8; ++j) {
    int k = c * 32 + lg * 8 + j;
    float v = (col < 9) ? g1[k] * w2[k * 9 + col] : 0.f;
    _Float16 hi = (_Float16)v;
    H[j] = hi;
    L[j] = (_Float16)(v - (float)hi);
  }
  *(f16x8*)(fh + (size_t)t * 8) = H;
  *(f16x8*)(fl + (size_t)t * 8) = L;
}

// ---------------- prep: cg[j] = sum_k g1[k]*W2[k][j], cb[j] = sum_k be1[k]*W2[k][j]  (f64) ----------------
__global__ void k_cgcb(const float* __restrict__ w2, const float* __restrict__ g1,
                       const float* __restrict__ be1, double* __restrict__ cgcb) {
  int l = threadIdx.x;  // 64 threads, 1 block
  double cg[9], cb[9];
#pragma unroll
  for (int j = 0; j < 9; ++j) { cg[j] = 0.0; cb[j] = 0.0; }
  for (int i = 0; i < 32; ++i) {
    int k = i * 64 + l;
    double g = (double)g1[k], b = (double)be1[k];
#pragma unroll
    for (int j = 0; j < 9; ++j) {
      double w = (double)w2[k * 9 + j];
      cg[j] += g * w;
      cb[j] += b * w;
    }
  }
  for (int off = 32; off; off >>= 1) {
#pragma unroll
    for (int j = 0; j < 9; ++j) {
      cg[j] += __shfl_xor(cg[j], off, 64);
      cb[j] += __shfl_xor(cb[j], off, 64);
    }
  }
  if (l == 0) {
    for (int j = 0; j < 16; ++j) {
      cgcb[j] = (j < 9) ? cg[j] : 0.0;
      cgcb[16 + j] = (j < 9) ? cb[j] : 0.0;
    }
  }
}

// ---------------- GEMM1 + fused GEMM2-partial: 3-term split-fp16, 16x16x32 MFMA ----------------
// Round-5 structure exactly (best measured): 256x256 tile, BK=32, 8 waves, dbuf LDS,
// counted vmcnt(2), raw barriers, STAGE interleaved with MFMA clusters, granule swizzle.
// fp16 split (e5m10): D = Ah*Bh + Ah*Bl + Al*Bh; dropped Al*Bl term is ~2^-22 relative.
// Epilogue: relu -> LDS f32 tile -> GEMM2 partial dots + stats (no hbuf).
__global__ __launch_bounds__(512, 2) void k_gemm1(const u16* __restrict__ xh, const u16* __restrict__ xl,
                                                  const u16* __restrict__ wh, const u16* __restrict__ wl,
                                                  const float* __restrict__ b1,
                                                  const u16* __restrict__ fh, const u16* __restrict__ fl,
                                                  float* __restrict__ pdot, float* __restrict__ pstat) {
  __shared__ __align__(16) u16 lds[2][4][8192];  // [buf][Ah,Al,Bh,Bl][256 rows * 32 k] = 128 KiB
  const int tid = threadIdx.x;
  // XCD swizzle (bijective, nwg=1024): per-XCD chunk covers 16 m-tiles x all 8 n-tiles
  const int swz = ((blockIdx.x & 7) << 7) | (blockIdx.x >> 3);
  const int m0 = (swz >> 3) << 8;
  const int n0 = (swz & 7) << 8;
  const int lane = tid & 63, w = tid >> 6;
  const int wr = (w >> 2) << 7;  // 0 or 128
  const int wc = (w & 3) << 6;   // 0,64,128,192
  const int lr = lane & 15, lg = lane >> 4;

  // tile-invariant LDS read offsets (u16 units), with conflict swizzle
  int a_off[8], b_off[4];
#pragma unroll
  for (int i = 0; i < 8; ++i) {
    int row = wr + i * 16 + lr;
    a_off[i] = row * 32 + ((lg ^ ((row >> 1) & 3)) << 3);
  }
#pragma unroll
  for (int j = 0; j < 4; ++j) {
    int row = wc + j * 16 + lr;
    b_off[j] = row * 32 + ((lg ^ ((row >> 1) & 3)) << 3);
  }

  // staging: 2 granules (16B) per thread per matrix; rows tid>>2 and tid>>2+128
  const size_t aoff = (size_t)(m0 + (tid >> 2)) * 1024 + ((tid & 3) << 3);
  const size_t boff = (size_t)(n0 + (tid >> 2)) * 1024 + ((tid & 3) << 3);

#define STAGE1(bf, mt, src, off, kk)                          \
  do {                                                        \
    GLD16((src) + (off) + (kk), &lds[bf][mt][tid * 8]);       \
    GLD16((src) + (off) + 131072 + (kk), &lds[bf][mt][4096 + tid * 8]); \
  } while (0)

  // prologue: stage K-tile 0 into buf 0 (8 loads/thread, oldest in vmcnt order)
  STAGE1(0, 0, xh, aoff, 0);
  STAGE1(0, 1, xl, aoff, 0);
  STAGE1(0, 2, wh, boff, 0);
  STAGE1(0, 3, wl, boff, 0);

  f32x4 acc[8][4] = {};
#pragma unroll 2
  for (int kt = 0; kt < 32; ++kt) {
    const int cur = kt & 1, nxt = cur ^ 1;
    const int nk = (kt < 31 ? kt + 1 : 31) * 32;  // last iter: benign re-stage of tile 31
    // prefetch next tile Ah BEFORE the wait -> these stay in flight across the barrier
    STAGE1(nxt, 0, xh, aoff, nk);
    asm volatile("s_waitcnt vmcnt(2)" ::: "memory");  // retire current tile's 8 loads only
    __builtin_amdgcn_s_barrier();                     // raw: no vmcnt(0) drain
    asm volatile("" ::: "memory");
    const u16* Ah = &lds[cur][0][0];
    const u16* Al = &lds[cur][1][0];
    const u16* Bh = &lds[cur][2][0];
    const u16* Bl = &lds[cur][3][0];
    f16x8 ahf[4], alf[4], bhf[4], blf[4];
#pragma unroll
    for (int j = 0; j < 4; ++j) {
      bhf[j] = *(const f16x8*)(Bh + b_off[j]);
      blf[j] = *(const f16x8*)(Bl + b_off[j]);
    }
#pragma unroll
    for (int i = 0; i < 4; ++i) {
      ahf[i] = *(const f16x8*)(Ah + a_off[i]);
      alf[i] = *(const f16x8*)(Al + a_off[i]);
    }
    // P0: MFMA lower 4 row-frags x j0-1; prefetch Al
    STAGE1(nxt, 1, xl, aoff, nk);
    __builtin_amdgcn_s_setprio(1);
#pragma unroll
    for (int i = 0; i < 4; ++i)
#pragma unroll
      for (int j = 0; j < 2; ++j) {
        acc[i][j] = MFMA_F16(ahf[i], bhf[j], acc[i][j]);
        acc[i][j] = MFMA_F16(ahf[i], blf[j], acc[i][j]);
        acc[i][j] = MFMA_F16(alf[i], bhf[j], acc[i][j]);
      }
    __builtin_amdgcn_s_setprio(0);
    // P1: prefetch Bh; MFMA lower x j2-3
    STAGE1(nxt, 2, wh, boff, nk);
    __builtin_amdgcn_s_setprio(1);
#pragma unroll
    for (int i = 0; i < 4; ++i)
#pragma unroll
      for (int j = 2; j < 4; ++j) {
        acc[i][j] = MFMA_F16(ahf[i], bhf[j], acc[i][j]);
        acc[i][j] = MFMA_F16(ahf[i], blf[j], acc[i][j]);
        acc[i][j] = MFMA_F16(alf[i], bhf[j], acc[i][j]);
      }
    __builtin_amdgcn_s_setprio(0);
    // P2: prefetch Bl; read A upper half; MFMA upper x j0-1
    STAGE1(nxt, 3, wl, boff, nk);
#pragma unroll
    for (int i = 0; i < 4; ++i) {
      ahf[i] = *(const f16x8*)(Ah + a_off[i + 4]);
      alf[i] = *(const f16x8*)(Al + a_off[i + 4]);
    }
    __builtin_amdgcn_s_setprio(1);
#pragma unroll
    for (int i = 0; i < 4; ++i)
#pragma unroll
      for (int j = 0; j < 2; ++j) {
        acc[i + 4][j] = MFMA_F16(ahf[i], bhf[j], acc[i + 4][j]);
        acc[i + 4][j] = MFMA_F16(ahf[i], blf[j], acc[i + 4][j]);
        acc[i + 4][j] = MFMA_F16(alf[i], bhf[j], acc[i + 4][j]);
      }
    __builtin_amdgcn_s_setprio(0);
    // P3: MFMA upper x j2-3
    __builtin_amdgcn_s_setprio(1);
#pragma unroll
    for (int i = 0; i < 4; ++i)
#pragma unroll
      for (int j = 2; j < 4; ++j) {
        acc[i + 4][j] = MFMA_F16(ahf[i], bhf[j], acc[i + 4][j]);
        acc[i + 4][j] = MFMA_F16(ahf[i], blf[j], acc[i + 4][j]);
        acc[i + 4][j] = MFMA_F16(alf[i], bhf[j], acc[i + 4][j]);
      }
    __builtin_amdgcn_s_setprio(0);
    asm volatile("" ::: "memory");
    __builtin_amdgcn_s_barrier();  // all waves done reading buf[cur] -> next tile may overwrite
  }
#undef STAGE1

  // ======== fused epilogue: relu + GEMM2-partial + stats (no hbuf) ========
  asm volatile("s_waitcnt vmcnt(0)" ::: "memory");  // drain in-flight global_load_lds
  __syncthreads();                                  // LDS now free for reuse
  float* vt = (float*)&lds[0][0][0];                // [256 rows][128 cols f32], granule-swizzled

  // E0: bias + relu in place
#pragma unroll
  for (int j = 0; j < 4; ++j) {
    const float bias = b1[n0 + wc + j * 16 + lr];
#pragma unroll
    for (int i = 0; i < 8; ++i)
#pragma unroll
      for (int r = 0; r < 4; ++r) acc[i][j][r] = fmaxf(acc[i][j][r] + bias, 0.f);
  }

  f32x4 acc2[2] = {};
  float sstat[2] = {0.f, 0.f}, qstat[2] = {0.f, 0.f};
  const int myrow0 = w * 32;  // reader rows: [w*32, w*32+32)

#pragma unroll
  for (int half = 0; half < 2; ++half) {
    // write phase: waves with (w&3)>>1 == half own cols [half*128, half*128+128)
    if (((w & 3) >> 1) == half) {
      const int colbase = wc & 127;
#pragma unroll
      for (int j = 0; j < 4; ++j) {
        const int lcol = colbase + j * 16 + lr;
        const int g = lcol >> 2, wsel = lcol & 3;
#pragma unroll
        for (int i = 0; i < 8; ++i)
#pragma unroll
          for (int r = 0; r < 4; ++r) {
            const int row = wr + i * 16 + lg * 4 + r;
            vt[row * 128 + ((g ^ (row & 7)) << 2) + wsel] = acc[i][j][r];
          }
      }
    }
    __syncthreads();
    // read phase: 4 k-blocks of 32 cols
#pragma unroll
    for (int cl = 0; cl < 4; ++cl) {
      const int cglob = (n0 >> 5) + half * 4 + cl;
      const f16x8 bh = *(const f16x8*)(fh + (size_t)(cglob * 64 + lane) * 8);
      const f16x8 bl = *(const f16x8*)(fl + (size_t)(cglob * 64 + lane) * 8);
#pragma unroll
      for (int g2 = 0; g2 < 2; ++g2) {
        const int row = myrow0 + g2 * 16 + lr;
        const int g0 = cl * 8 + lg * 2;
        const float4 f0 = *(const float4*)&vt[row * 128 + ((g0 ^ (row & 7)) << 2)];
        const float4 f1 = *(const float4*)&vt[row * 128 + (((g0 + 1) ^ (row & 7)) << 2)];
        float f[8] = {f0.x, f0.y, f0.z, f0.w, f1.x, f1.y, f1.z, f1.w};
        f16x8 AH, AL;
#pragma unroll
        for (int e = 0; e < 8; ++e) {
          sstat[g2] += f[e];
          qstat[g2] = fmaf(f[e], f[e], qstat[g2]);
          _Float16 hi = (_Float16)f[e];
          AH[e] = hi;
          AL[e] = (_Float16)(f[e] - (float)hi);
        }
        acc2[g2] = MFMA_F16(AH, bh, acc2[g2]);
        acc2[g2] = MFMA_F16(AH, bl, acc2[g2]);
        acc2[g2] = MFMA_F16(AL, bh, acc2[g2]);
      }
    }
    __syncthreads();
  }

  // stats reduce over the 4 lg-lanes (same lr = same row)
#pragma unroll
  for (int g2 = 0; g2 < 2; ++g2) {
    sstat[g2] += __shfl_xor(sstat[g2], 16, 64);
    sstat[g2] += __shfl_xor(sstat[g2], 32, 64);
    qstat[g2] += __shfl_xor(qstat[g2], 16, 64);
    qstat[g2] += __shfl_xor(qstat[g2], 32, 64);
  }
  const int ntile = n0 >> 8;
#pragma unroll
  for (int g2 = 0; g2 < 2; ++g2) {
    if (lg == 0) {
      const int row = m0 + myrow0 + g2 * 16 + lr;
      *(float2*)&pstat[((size_t)row * 8 + ntile) * 2] = make_float2(sstat[g2], qstat[g2]);
    }
    if (lr < 9) {
#pragma unroll
      for (int r = 0; r < 4; ++r) {
        const int row = m0 + myrow0 + g2 * 16 + lg * 4 + r;
        pdot[((size_t)row * 8 + ntile) * 12 + lr] = acc2[g2][r];
      }
    }
  }
}

// ---------------- f64 3x3 SVD -> nearest SO(3) rotation ----------------
static __device__ __forceinline__ void jrot(double S[3][3], double V[3][3], int p, int q, int r) {
  double apq = S[p][q];
  if (apq == 0.0) return;
  double tau = (S[q][q] - S[p][p]) / (2.0 * apq);
  double t = (tau >= 0.0 ? 1.0 : -1.0) / (fabs(tau) + sqrt(1.0 + tau * tau));
  double c = 1.0 / sqrt(1.0 + t * t);
  double s = t * c;
  double spp = S[p][p], sqq = S[q][q];
  double srp = S[r][p], srq = S[r][q];
  S[p][p] = spp - t * apq;
  S[q][q] = sqq + t * apq;
  S[p][q] = 0.0; S[q][p] = 0.0;
  S[r][p] = c * srp - s * srq; S[p][r] = S[r][p];
  S[r][q] = s * srp + c * srq; S[q][r] = S[r][q];
#pragma unroll
  for (int i = 0; i < 3; ++i) {
    double vip = V[i][p], viq = V[i][q];
    V[i][p] = c * vip - s * viq;
    V[i][q] = s * vip + c * viq;
  }
}

static __device__ void svd_so3(const double* Rf, float* Of) {
  double A[3][3], S[3][3];
  double V[3][3] = {{1, 0, 0}, {0, 1, 0}, {0, 0, 1}};
#pragma unroll
  for (int i = 0; i < 3; ++i)
#pragma unroll
    for (int j = 0; j < 3; ++j) A[i][j] = Rf[i * 3 + j];
#pragma unroll
  for (int p = 0; p < 3; ++p)
#pragma unroll
    for (int q = 0; q < 3; ++q) {
      double sa = 0.0;
#pragma unroll
      for (int i = 0; i < 3; ++i) sa += A[i][p] * A[i][q];
      S[p][q] = sa;
    }
  for (int it = 0; it < 6; ++it) {
    jrot(S, V, 0, 1, 2);
    jrot(S, V, 0, 2, 1);
    jrot(S, V, 1, 2, 0);
  }
  double l0 = S[0][0], l1 = S[1][1], l2 = S[2][2];
  double c0[3] = {V[0][0], V[1][0], V[2][0]};
  double c1[3] = {V[0][1], V[1][1], V[2][1]};
  double c2[3] = {V[0][2], V[1][2], V[2][2]};
  double tl, tv;
#define SWP(la, lb, ca, cb)                                         \
  if (la < lb) {                                                    \
    tl = la; la = lb; lb = tl;                                      \
    tv = ca[0]; ca[0] = cb[0]; cb[0] = tv;                          \
    tv = ca[1]; ca[1] = cb[1]; cb[1] = tv;                          \
    tv = ca[2]; ca[2] = cb[2]; cb[2] = tv;                          \
  }
  SWP(l0, l1, c0, c1)
  SWP(l0, l2, c0, c2)
  SWP(l1, l2, c1, c2)
#undef SWP
  double v3[3];
  v3[0] = c0[1] * c1[2] - c0[2] * c1[1];
  v3[1] = c0[2] * c1[0] - c0[0] * c1[2];
  v3[2] = c0[0] * c1[1] - c0[1] * c1[0];
  double t1[3], t2[3];
#pragma unroll
  for (int i = 0; i < 3; ++i) {
    t1[i] = A[i][0] * c0[0] + A[i][1] * c0[1] + A[i][2] * c0[2];
    t2[i] = A[i][0] * c1[0] + A[i][1] * c1[1] + A[i][2] * c1[2];
  }
  double n1 = sqrt(t1[0] * t1[0] + t1[1] * t1[1] + t1[2] * t1[2]);
  if (n1 < 1e-20) {
#pragma unroll
    for (int t = 0; t < 9; ++t) Of[t] = (t == 0 || t == 4 || t == 8) ? 1.f : 0.f;
    return;
  }
  double u1[3], u2[3], u3[3];
  double r1 = 1.0 / n1;
#pragma unroll
  for (int i = 0; i < 3; ++i) u1[i] = t1[i] * r1;
  double d12 = u1[0] * t2[0] + u1[1] * t2[1] + u1[2] * t2[2];
#pragma unroll
  for (int i = 0; i < 3; ++i) t2[i] -= d12 * u1[i];
  double n2 = sqrt(t2[0] * t2[0] + t2[1] * t2[1] + t2[2] * t2[2]);
  if (n2 > 1e-14 * n1) {
    double r2 = 1.0 / n2;
#pragma unroll
    for (int i = 0; i < 3; ++i) u2[i] = t2[i] * r2;
  } else {
    double ax = fabs(u1[0]), ay = fabs(u1[1]), az = fabs(u1[2]);
    double e[3] = {0.0, 0.0, 0.0};
    if (ax <= ay && ax <= az) e[0] = 1.0;
    else if (ay <= az) e[1] = 1.0;
    else e[2] = 1.0;
    double d = e[0] * u1[0] + e[1] * u1[1] + e[2] * u1[2];
#pragma unroll
    for (int i = 0; i < 3; ++i) e[i] -= d * u1[i];
    double nn = 1.0 / sqrt(e[0] * e[0] + e[1] * e[1] + e[2] * e[2]);
#pragma unroll
    for (int i = 0; i < 3; ++i) u2[i] = e[i] * nn;
  }
  u3[0] = u1[1] * u2[2] - u1[2] * u2[1];
  u3[1] = u1[2] * u2[0] - u1[0] * u2[2];
  u3[2] = u1[0] * u2[1] - u1[1] * u2[0];
#pragma unroll
  for (int i = 0; i < 3; ++i)
#pragma unroll
    for (int j = 0; j < 3; ++j)
      Of[i * 3 + j] = (float)(u1[i] * c0[j] + u2[i] * c1[j] + u3[i] * v3[j]);
}

// ---------------- combine: f64 sum of partials + LN1-fold + LN2 + SVD, 1 thread/row ----------------
__global__ __launch_bounds__(256) void k_comb(const float* __restrict__ pdot,
                                              const float* __restrict__ pstat,
                                              const double* __restrict__ cgcb,
                                              const float* __restrict__ b2,
                                              const float* __restrict__ g2v,
                                              const float* __restrict__ be2,
                                              float* __restrict__ out) {
  const int row = blockIdx.x * 256 + threadIdx.x;
  double dj[9];
#pragma unroll
  for (int j = 0; j < 9; ++j) dj[j] = 0.0;
  double s = 0.0, q = 0.0;
#pragma unroll
  for (int nt = 0; nt < 8; ++nt) {
    const float* p = pdot + ((size_t)row * 8 + nt) * 12;
#pragma unroll
    for (int j = 0; j < 9; ++j) dj[j] += (double)p[j];
    const float* ps = pstat + ((size_t)row * 8 + nt) * 2;
    s += (double)ps[0];
    q += (double)ps[1];
  }
  const double mean = s * (1.0 / 2048.0);
  const double varr = fmax(q * (1.0 / 2048.0) - mean * mean, 0.0);
  const double inv = 1.0 / sqrt(varr + 1e-5);
  double a2[9];
  double s9 = 0.0, q9 = 0.0;
#pragma unroll
  for (int j = 0; j < 9; ++j) {
    double v = inv * (dj[j] - mean * cgcb[j]) + cgcb[16 + j] + (double)b2[j];
    v = fmax(v, 0.0);
    a2[j] = v;
    s9 += v;
    q9 += v * v;
  }
  const double m2 = s9 * (1.0 / 9.0);
  const double v2c = fmax(q9 * (1.0 / 9.0) - m2 * m2, 0.0);
  const double i2 = 1.0 / sqrt(v2c + 1e-5);
  double rn[9];
#pragma unroll
  for (int j = 0; j < 9; ++j) rn[j] = (a2[j] - m2) * i2 * (double)g2v[j] + (double)be2[j];
  float O[9];
  svd_so3(rn, O);
  float* op = out + (size_t)row * 9;
#pragma unroll
  for (int t = 0; t < 9; ++t) op[t] = O[t];
}

// ---------------- host ----------------
extern "C" void kernel_launch(void* const* d_in, const int* in_sizes, int n_in,
                              void* d_out, int out_size, void* d_ws, size_t ws_size,
                              hipStream_t stream) {
  const float* x   = (const float*)d_in[0];
  const float* W1  = (const float*)d_in[1];
  const float* b1  = (const float*)d_in[2];
  const float* g1  = (const float*)d_in[3];
  const float* be1 = (const float*)d_in[4];
  const float* W2  = (const float*)d_in[5];
  const float* b2  = (const float*)d_in[6];
  const float* g2  = (const float*)d_in[7];
  const float* be2 = (const float*)d_in[8];
  float* out = (float*)d_out;
  char* ws = (char*)d_ws;
  u16*    xh   = (u16*)(ws + 0);             // 67108864 B
  u16*    xl   = (u16*)(ws + 67108864);      // 67108864
  u16*    wh   = (u16*)(ws + 134217728);     // 4194304
  u16*    wl   = (u16*)(ws + 138412032);     // 4194304
  u16*    fh   = (u16*)(ws + 142606336);     // 65536
  u16*    fl   = (u16*)(ws + 142671872);     // 65536
  double* cgcb = (double*)(ws + 142737408);  // 256 B
  float*  pdot = (float*)(ws + 142737664);   // 32768*8*12*4 = 12582912
  float*  pstat= (float*)(ws + 155320576);   // 32768*8*2*4  = 2097152

  k_split_x<<<dim3(16384), dim3(256), 0, stream>>>(x, xh, xl);
  k_split_w1t<<<dim3(2048), dim3(256), 0, stream>>>(W1, wh, wl);
  k_w2frag<<<dim3(16), dim3(256), 0, stream>>>(W2, g1, fh, fl);
  k_cgcb<<<dim3(1), dim3(64), 0, stream>>>(W2, g1, be1, cgcb);
  k_gemm1<<<dim3(1024), dim3(512), 0, stream>>>(xh, xl, wh, wl, b1, fh, fl, pdot, pstat);
  k_comb<<<dim3(128), dim3(256), 0, stream>>>(pdot, pstat, cgcb, b2, g2, be2, out);
}